// Round 1
// baseline (2497.668 us; speedup 1.0000x reference)
//
#include <hip/hip_runtime.h>
#include <math.h>

#define E_DIM 1024
#define H_DIM 64
#define S_LEN 4096
#define B_SZ  4

constexpr int ROWS = 32;   // rows of x per block in projection
constexpr int KT   = 64;   // K-tile in projection

// ---------------------------------------------------------------------------
// Kernel A: QKV projection.  q/k/v[b,s,h] = x[b,s,:] @ W[:,h] + bias[h]
// 256 threads, 32 rows per block. Lane owns h = tid&63; row-group rg = tid>>6
// owns rows rg*8 + j (j=0..7).
// LDS: xs[32][64] (8KB) + 3x W-tile[64][64] (48KB) = 56KB -> 2 blocks/CU.
// xs reads are wave-broadcast (free); W reads are h-consecutive (2-way, free).
// ---------------------------------------------------------------------------
__global__ __launch_bounds__(256) void qkv_proj_kernel(
    const float* __restrict__ x,
    const float* __restrict__ Wq, const float* __restrict__ bq,
    const float* __restrict__ Wk, const float* __restrict__ bk,
    const float* __restrict__ Wv, const float* __restrict__ bv,
    float* __restrict__ qo, float* __restrict__ ko, float* __restrict__ vo)
{
    __shared__ float xs[ROWS][KT];
    __shared__ float wsq[KT][H_DIM];
    __shared__ float wsk[KT][H_DIM];
    __shared__ float wsv[KT][H_DIM];

    const int tid = threadIdx.x;
    const int h   = tid & 63;
    const int rg  = tid >> 6;                  // 0..3
    const long row0 = (long)blockIdx.x * ROWS;

    float accq[8], acck[8], accv[8];
#pragma unroll
    for (int j = 0; j < 8; ++j) { accq[j] = 0.f; acck[j] = 0.f; accv[j] = 0.f; }

    for (int kt = 0; kt < E_DIM; kt += KT) {
        __syncthreads();   // protect LDS from previous iteration's readers
        // ---- load xs: 32x64 floats = 512 float4, 2 per thread, coalesced
#pragma unroll
        for (int i = 0; i < 2; ++i) {
            int idx4 = tid + 256 * i;          // 0..511
            int r    = idx4 >> 4;              // 16 float4 per row
            int c4   = idx4 & 15;
            float4 val = *reinterpret_cast<const float4*>(
                &x[(row0 + r) * (long)E_DIM + kt + c4 * 4]);
            *reinterpret_cast<float4*>(&xs[r][c4 * 4]) = val;
        }
        // ---- load W tiles: each 64x64 floats = 1024 float4, 4 per thread
#pragma unroll
        for (int i = 0; i < 4; ++i) {
            int idx4 = tid + 256 * i;          // 0..1023
            int kr   = idx4 >> 4;              // 16 float4 per row of 64
            int c4   = idx4 & 15;
            long g   = (long)(kt + kr) * H_DIM + c4 * 4;
            *reinterpret_cast<float4*>(&wsq[kr][c4 * 4]) =
                *reinterpret_cast<const float4*>(&Wq[g]);
            *reinterpret_cast<float4*>(&wsk[kr][c4 * 4]) =
                *reinterpret_cast<const float4*>(&Wk[g]);
            *reinterpret_cast<float4*>(&wsv[kr][c4 * 4]) =
                *reinterpret_cast<const float4*>(&Wv[g]);
        }
        __syncthreads();
        // ---- accumulate
#pragma unroll 4
        for (int kk = 0; kk < KT; ++kk) {
            float wq = wsq[kk][h];
            float wk = wsk[kk][h];
            float wv = wsv[kk][h];
#pragma unroll
            for (int j = 0; j < 8; ++j) {
                float xv = xs[rg * 8 + j][kk];
                accq[j] = fmaf(xv, wq, accq[j]);
                acck[j] = fmaf(xv, wk, acck[j]);
                accv[j] = fmaf(xv, wv, accv[j]);
            }
        }
    }

    const float bqv = bq[h], bkv = bk[h], bvv = bv[h];
#pragma unroll
    for (int j = 0; j < 8; ++j) {
        long row = row0 + rg * 8 + j;
        qo[row * H_DIM + h] = accq[j] + bqv;
        ko[row * H_DIM + h] = acck[j] + bkv;
        vo[row * H_DIM + h] = accv[j] + bvv;
    }
}

// ---------------------------------------------------------------------------
// Kernel B: causal flash attention, fp32, one wave per query row, lane = h.
// Per key j: coalesced 256B k/v loads (L2-resident), 6-stage shfl_xor reduce,
// online softmax in registers. Load balanced: each wave handles rows
// (idx, S-1-idx) -> uniform 4097 keys/wave.
// ---------------------------------------------------------------------------
__device__ inline void attn_one_row(const float* __restrict__ qb,
                                    const float* __restrict__ kb,
                                    const float* __restrict__ vb,
                                    float* __restrict__ ob,
                                    int qi, int lane)
{
    float ql = qb[(long)qi * H_DIM + lane];
    float m = -INFINITY, lsum = 0.f, acc = 0.f;
    for (int j = 0; j <= qi; ++j) {
        float kv = kb[(long)j * H_DIM + lane];
        float s  = ql * kv;
#pragma unroll
        for (int off = 32; off > 0; off >>= 1)
            s += __shfl_xor(s, off, 64);
        s *= 0.125f;                       // 1/sqrt(64)
        float m_new = fmaxf(m, s);
        float corr  = __expf(m - m_new);   // first iter: exp(-inf)=0
        float p     = __expf(s - m_new);
        float vv    = vb[(long)j * H_DIM + lane];
        lsum = lsum * corr + p;
        acc  = acc * corr + p * vv;
        m = m_new;
    }
    ob[(long)qi * H_DIM + lane] = acc / lsum;
}

__global__ __launch_bounds__(256) void attn_fwd_kernel(
    const float* __restrict__ q, const float* __restrict__ k,
    const float* __restrict__ v, float* __restrict__ out)
{
    const int wid  = (int)((blockIdx.x * blockDim.x + threadIdx.x) >> 6);
    const int lane = threadIdx.x & 63;
    const int b    = wid >> 11;            // 2048 row-pairs per batch
    const int idx  = wid & 2047;

    const long base = (long)b * S_LEN * H_DIM;
    const float* qb = q + base;
    const float* kb = k + base;
    const float* vb = v + base;
    float* ob = out + base;

    attn_one_row(qb, kb, vb, ob, idx, lane);                 // short row
    attn_one_row(qb, kb, vb, ob, S_LEN - 1 - idx, lane);     // long row
}

// ---------------------------------------------------------------------------
extern "C" void kernel_launch(void* const* d_in, const int* in_sizes, int n_in,
                              void* d_out, int out_size, void* d_ws, size_t ws_size,
                              hipStream_t stream)
{
    const float* x  = (const float*)d_in[0];
    const float* Wq = (const float*)d_in[1];
    const float* bq = (const float*)d_in[2];
    const float* Wk = (const float*)d_in[3];
    const float* bk = (const float*)d_in[4];
    const float* Wv = (const float*)d_in[5];
    const float* bv = (const float*)d_in[6];
    float* out = (float*)d_out;

    const long BSH = (long)B_SZ * S_LEN * H_DIM;   // 1,048,576
    float* qs = (float*)d_ws;
    float* ks = qs + BSH;
    float* vs = ks + BSH;

    const int total_rows = B_SZ * S_LEN;           // 16384
    qkv_proj_kernel<<<total_rows / ROWS, 256, 0, stream>>>(
        x, Wq, bq, Wk, bk, Wv, bv, qs, ks, vs);

    const int waves = B_SZ * S_LEN / 2;            // 8192 row-pairs
    attn_fwd_kernel<<<waves / 4, 256, 0, stream>>>(qs, ks, vs, out);
}

// Round 2
// 251.118 us; speedup vs baseline: 9.9462x; 9.9462x over previous
//
#include <hip/hip_runtime.h>
#include <math.h>

#define E_DIM 1024
#define H_DIM 64
#define S_LEN 4096
#define B_SZ  4

typedef short s16x8 __attribute__((ext_vector_type(8)));
typedef float f32x4 __attribute__((ext_vector_type(4)));
typedef unsigned short u16;

static __device__ __forceinline__ u16 f2b(float f) {
    unsigned int u = __builtin_bit_cast(unsigned int, f);
    u += 0x7fffu + ((u >> 16) & 1u);        // RNE
    return (u16)(u >> 16);
}

// ---------------------------------------------------------------------------
// Kernel A: QKV projection (fp32 accumulate, bf16 output).
// ---------------------------------------------------------------------------
constexpr int ROWS = 32;
constexpr int KT   = 64;

__global__ __launch_bounds__(256) void qkv_proj_kernel(
    const float* __restrict__ x,
    const float* __restrict__ Wq, const float* __restrict__ bq,
    const float* __restrict__ Wk, const float* __restrict__ bk,
    const float* __restrict__ Wv, const float* __restrict__ bv,
    u16* __restrict__ qo, u16* __restrict__ ko, u16* __restrict__ vo)
{
    __shared__ float xs[ROWS][KT];
    __shared__ float wsq[KT][H_DIM];
    __shared__ float wsk[KT][H_DIM];
    __shared__ float wsv[KT][H_DIM];

    const int tid = threadIdx.x;
    const int h   = tid & 63;
    const int rg  = tid >> 6;
    const long row0 = (long)blockIdx.x * ROWS;

    float accq[8], acck[8], accv[8];
#pragma unroll
    for (int j = 0; j < 8; ++j) { accq[j] = 0.f; acck[j] = 0.f; accv[j] = 0.f; }

    for (int kt = 0; kt < E_DIM; kt += KT) {
        __syncthreads();
#pragma unroll
        for (int i = 0; i < 2; ++i) {
            int idx4 = tid + 256 * i;
            int r    = idx4 >> 4;
            int c4   = idx4 & 15;
            float4 val = *reinterpret_cast<const float4*>(
                &x[(row0 + r) * (long)E_DIM + kt + c4 * 4]);
            *reinterpret_cast<float4*>(&xs[r][c4 * 4]) = val;
        }
#pragma unroll
        for (int i = 0; i < 4; ++i) {
            int idx4 = tid + 256 * i;
            int kr   = idx4 >> 4;
            int c4   = idx4 & 15;
            long g   = (long)(kt + kr) * H_DIM + c4 * 4;
            *reinterpret_cast<float4*>(&wsq[kr][c4 * 4]) =
                *reinterpret_cast<const float4*>(&Wq[g]);
            *reinterpret_cast<float4*>(&wsk[kr][c4 * 4]) =
                *reinterpret_cast<const float4*>(&Wk[g]);
            *reinterpret_cast<float4*>(&wsv[kr][c4 * 4]) =
                *reinterpret_cast<const float4*>(&Wv[g]);
        }
        __syncthreads();
#pragma unroll 4
        for (int kk = 0; kk < KT; ++kk) {
            float wq = wsq[kk][h];
            float wk = wsk[kk][h];
            float wv = wsv[kk][h];
#pragma unroll
            for (int j = 0; j < 8; ++j) {
                float xv = xs[rg * 8 + j][kk];
                accq[j] = fmaf(xv, wq, accq[j]);
                acck[j] = fmaf(xv, wk, acck[j]);
                accv[j] = fmaf(xv, wv, accv[j]);
            }
        }
    }

    const float bqv = bq[h], bkv = bk[h], bvv = bv[h];
#pragma unroll
    for (int j = 0; j < 8; ++j) {
        long row = row0 + rg * 8 + j;
        qo[row * H_DIM + h] = f2b(accq[j] + bqv);
        ko[row * H_DIM + h] = f2b(acck[j] + bkv);
        vo[row * H_DIM + h] = f2b(accv[j] + bvv);
    }
}

// ---------------------------------------------------------------------------
// Kernel B: causal flash attention, bf16 MFMA (16x16x32), fp32 accum.
// 256 blocks x 4 waves; wave owns 16 q rows (qw = q0 + 16*w).
// KV tiles of 32 keys staged in LDS (K xor-swizzled rows; V transposed).
// S^T = K . Q^T  so scores sit at col=q (lane&15): row reduce = 2 shfl_xor.
// P re-laid out via per-wave LDS buffer for the PV MFMA A-operand.
// ---------------------------------------------------------------------------
constexpr int QB = 64;
constexpr int KB = 32;

#define LDS_K 0        // 32 keys * 128B (xor-swizzled 16B chunks)   -> 4096B
#define LDS_V 4096     // Vt[h=64][key=32 +pad] rows of 80B          -> 5120B
#define LDS_P 9216     // per-wave P[q=16][k=32 +pad] rows of 80B x4 -> 5120B

__global__ __launch_bounds__(256) void attn_mfma_kernel(
    const u16* __restrict__ q, const u16* __restrict__ k,
    const u16* __restrict__ v, float* __restrict__ out)
{
    __shared__ __align__(16) char smem[14336];

    const int tid  = threadIdx.x;
    const int lane = tid & 63;
    const int w    = tid >> 6;
    const int l15  = lane & 15;
    const int g    = lane >> 4;          // 0..3

    const int blk = blockIdx.x;
    const int b   = blk >> 6;
    const int q0  = (blk & 63) * QB;
    const long base = (long)b * S_LEN * H_DIM;
    const int qw  = q0 + 16 * w;         // wave's first q row (in batch)

    // Q fragments (B-operand of S^T mfma): rows qw + l15
    const u16* qrow = q + base + (long)(qw + l15) * H_DIM;
    s16x8 qa0 = *(const s16x8*)(qrow + g * 8);        // e = g*8..+7
    s16x8 qa1 = *(const s16x8*)(qrow + 32 + g * 8);   // e = 32+g*8..+7

    f32x4 o0 = {0.f,0.f,0.f,0.f}, o1 = o0, o2 = o0, o3 = o0;
    float m = -INFINITY, lacc = 0.f;

    // staging thread mapping
    const int skey = tid >> 3;           // K: 0..31
    const int sc   = tid & 7;
    const int vkey = tid & 31;           // V: 0..31
    const int vc   = tid >> 5;           // 0..7

    const int T = q0 / KB + 2;           // tiles incl. diagonal

    for (int t = 0; t < T; ++t) {
        const int kv0 = t * KB;
        __syncthreads();                 // LDS reuse guard
        // ---- stage K tile (xor-swizzled 16B chunks within 128B rows)
        {
            const u16* kp = k + base + (long)(kv0 + skey) * H_DIM + sc * 8;
            uint4 kd = *(const uint4*)kp;
            *(uint4*)(smem + LDS_K + skey * 128 + ((sc ^ (skey & 7)) << 4)) = kd;
        }
        // ---- stage V transposed: Vt[h][key]
        {
            const u16* vp = v + base + (long)(kv0 + vkey) * H_DIM + vc * 8;
            s16x8 vd = *(const s16x8*)vp;
#pragma unroll
            for (int j = 0; j < 8; ++j)
                *(u16*)(smem + LDS_V + (vc * 8 + j) * 80 + vkey * 2) = (u16)vd[j];
        }
        __syncthreads();

        if (kv0 <= qw + 15) {
            // ---- S^T = K . Q^T : two 16-key tiles, two 32-e steps each
            f32x4 st0 = {0.f,0.f,0.f,0.f}, st1 = st0;
            {
                const int key0 = l15, key1 = 16 + l15;
                s16x8 ka;
                ka = *(const s16x8*)(smem + LDS_K + key0*128 + ((g     ^ (key0&7)) << 4));
                st0 = __builtin_amdgcn_mfma_f32_16x16x32_bf16(ka, qa0, st0, 0,0,0);
                ka = *(const s16x8*)(smem + LDS_K + key0*128 + (((4+g) ^ (key0&7)) << 4));
                st0 = __builtin_amdgcn_mfma_f32_16x16x32_bf16(ka, qa1, st0, 0,0,0);
                ka = *(const s16x8*)(smem + LDS_K + key1*128 + ((g     ^ (key1&7)) << 4));
                st1 = __builtin_amdgcn_mfma_f32_16x16x32_bf16(ka, qa0, st1, 0,0,0);
                ka = *(const s16x8*)(smem + LDS_K + key1*128 + (((4+g) ^ (key1&7)) << 4));
                st1 = __builtin_amdgcn_mfma_f32_16x16x32_bf16(ka, qa1, st1, 0,0,0);
            }
            // st[kt][r] = S^T[k_local = kt*16 + 4g + r][q = qw + l15]
            const int qg = qw + l15;
            float p[8];
#pragma unroll
            for (int r = 0; r < 4; ++r) {
                int kg = kv0 + 4 * g + r;
                p[r]     = (kg      <= qg) ? st0[r] * 0.125f : -INFINITY;
                p[4 + r] = (kg + 16 <= qg) ? st1[r] * 0.125f : -INFINITY;
            }
            float pm = p[0];
#pragma unroll
            for (int i = 1; i < 8; ++i) pm = fmaxf(pm, p[i]);
            pm = fmaxf(pm, __shfl_xor(pm, 16, 64));
            pm = fmaxf(pm, __shfl_xor(pm, 32, 64));
            const float mnew = fmaxf(m, pm);
            const float corr = __expf(m - mnew);   // t=0: exp(-inf)=0
            float psum = 0.f;
#pragma unroll
            for (int i = 0; i < 8; ++i) { p[i] = __expf(p[i] - mnew); psum += p[i]; }
            psum += __shfl_xor(psum, 16, 64);
            psum += __shfl_xor(psum, 32, 64);
            lacc = lacc * corr + psum;
            m = mnew;

            // ---- P (bf16) -> per-wave LDS, A-layout for PV
            char* pb = smem + LDS_P + w * 1280 + l15 * 80;
#pragma unroll
            for (int r = 0; r < 4; ++r) {
                *(u16*)(pb + (4 * g + r) * 2)        = f2b(p[r]);
                *(u16*)(pb + (16 + 4 * g + r) * 2)   = f2b(p[4 + r]);
            }
            asm volatile("s_waitcnt lgkmcnt(0)" ::: "memory");
            __builtin_amdgcn_sched_barrier(0);

            // ---- rescale O (rows q = 4g+r need corr from lane 4g+r)
#pragma unroll
            for (int r = 0; r < 4; ++r) {
                float cr = __shfl(corr, 4 * g + r, 64);
                o0[r] *= cr; o1[r] *= cr; o2[r] *= cr; o3[r] *= cr;
            }

            // ---- PV: O[16q x 64h] += P[16x32] . V[32x64]
            s16x8 pa  = *(const s16x8*)(smem + LDS_P + w * 1280 + l15 * 80 + g * 16);
            s16x8 vb0 = *(const s16x8*)(smem + LDS_V + (l15)      * 80 + g * 16);
            s16x8 vb1 = *(const s16x8*)(smem + LDS_V + (16 + l15) * 80 + g * 16);
            s16x8 vb2 = *(const s16x8*)(smem + LDS_V + (32 + l15) * 80 + g * 16);
            s16x8 vb3 = *(const s16x8*)(smem + LDS_V + (48 + l15) * 80 + g * 16);
            o0 = __builtin_amdgcn_mfma_f32_16x16x32_bf16(pa, vb0, o0, 0,0,0);
            o1 = __builtin_amdgcn_mfma_f32_16x16x32_bf16(pa, vb1, o1, 0,0,0);
            o2 = __builtin_amdgcn_mfma_f32_16x16x32_bf16(pa, vb2, o2, 0,0,0);
            o3 = __builtin_amdgcn_mfma_f32_16x16x32_bf16(pa, vb3, o3, 0,0,0);
        }
    }

    // ---- epilogue: divide by row sum, store fp32
    float* ob = out + base;
#pragma unroll
    for (int r = 0; r < 4; ++r) {
        float lr  = __shfl(lacc, 4 * g + r, 64);
        float inv = 1.0f / lr;
        long row  = qw + 4 * g + r;
        ob[row * H_DIM + l15]      = o0[r] * inv;
        ob[row * H_DIM + 16 + l15] = o1[r] * inv;
        ob[row * H_DIM + 32 + l15] = o2[r] * inv;
        ob[row * H_DIM + 48 + l15] = o3[r] * inv;
    }
}

// ---------------------------------------------------------------------------
extern "C" void kernel_launch(void* const* d_in, const int* in_sizes, int n_in,
                              void* d_out, int out_size, void* d_ws, size_t ws_size,
                              hipStream_t stream)
{
    const float* x  = (const float*)d_in[0];
    const float* Wq = (const float*)d_in[1];
    const float* bq = (const float*)d_in[2];
    const float* Wk = (const float*)d_in[3];
    const float* bk = (const float*)d_in[4];
    const float* Wv = (const float*)d_in[5];
    const float* bv = (const float*)d_in[6];
    float* out = (float*)d_out;

    const long BSH = (long)B_SZ * S_LEN * H_DIM;   // 1,048,576 elems
    u16* qs = (u16*)d_ws;
    u16* ks = qs + BSH;
    u16* vs = ks + BSH;

    const int total_rows = B_SZ * S_LEN;           // 16384
    qkv_proj_kernel<<<total_rows / ROWS, 256, 0, stream>>>(
        x, Wq, bq, Wk, bk, Wv, bv, qs, ks, vs);

    attn_mfma_kernel<<<total_rows / QB, 256, 0, stream>>>(qs, ks, vs, out);
}

// Round 3
// 232.630 us; speedup vs baseline: 10.7367x; 1.0795x over previous
//
#include <hip/hip_runtime.h>
#include <math.h>

#define E_DIM 1024
#define H_DIM 64
#define S_LEN 4096
#define B_SZ  4

typedef short s16x8 __attribute__((ext_vector_type(8)));
typedef short s16x4 __attribute__((ext_vector_type(4)));
typedef float f32x4 __attribute__((ext_vector_type(4)));
typedef unsigned short u16;
typedef unsigned int u32;

static __device__ __forceinline__ u16 f2b(float f) {
    u32 u = __builtin_bit_cast(u32, f);
    u += 0x7fffu + ((u >> 16) & 1u);        // RNE
    return (u16)(u >> 16);
}
static __device__ __forceinline__ u32 pk2(float lo, float hi) {
    return (u32)f2b(lo) | ((u32)f2b(hi) << 16);
}

#if defined(__has_builtin)
#  if __has_builtin(__builtin_amdgcn_mfma_f32_16x16x16bf16_1k)
#    define USE_1K 1
#  else
#    define USE_1K 0
#  endif
#else
#  define USE_1K 0
#endif

// ---------------------------------------------------------------------------
// Kernel 0: W transpose + bf16 convert.  Wt[mat*64+h][k] = bf16(W_mat[k][h])
// Coalesced reads (W is [k][h], h fastest), scattered 2B writes (fire+forget).
// ---------------------------------------------------------------------------
__global__ __launch_bounds__(256) void wt_kernel(
    const float* __restrict__ Wq, const float* __restrict__ Wk,
    const float* __restrict__ Wv, u16* __restrict__ wt)
{
    const int flat = blockIdx.x * 256 + threadIdx.x;   // 0..196607
    const int mat = flat >> 16;
    const int within = flat & 65535;                   // = k*64 + h
    const int kk = within >> 6;
    const int h  = within & 63;
    const float* W = (mat == 0) ? Wq : (mat == 1) ? Wk : Wv;
    wt[(long)(mat * 64 + h) * E_DIM + kk] = f2b(W[within]);
}

// ---------------------------------------------------------------------------
// Kernel 1: QKV projection via MFMA. One wave per 16 x-rows (1024 waves).
// A = Wt fragments (m = h), B = x fragments (n = row), D row = h, col = row.
// q,k stored row-major bf16; v stored TRANSPOSED Vt[b][h][s] bf16.
// ---------------------------------------------------------------------------
__global__ __launch_bounds__(64) void proj_kernel(
    const float* __restrict__ x, const u16* __restrict__ wt,
    const float* __restrict__ bq, const float* __restrict__ bk,
    const float* __restrict__ bv,
    u16* __restrict__ qs, u16* __restrict__ ks, u16* __restrict__ vt)
{
    const int lane = threadIdx.x;
    const int l15 = lane & 15, g = lane >> 4;
    const long row0 = (long)blockIdx.x * 16;
    const float* xr = x + (row0 + l15) * E_DIM;

    f32x4 z = {0.f, 0.f, 0.f, 0.f};
    f32x4 o[12];
#pragma unroll
    for (int i = 0; i < 12; ++i) o[i] = z;

    for (int ke = 0; ke < E_DIM; ke += 32) {
        const float4 fa = *(const float4*)(xr + ke + g * 8);
        const float4 fb = *(const float4*)(xr + ke + g * 8 + 4);
        s16x8 xa;
        xa[0] = (short)f2b(fa.x); xa[1] = (short)f2b(fa.y);
        xa[2] = (short)f2b(fa.z); xa[3] = (short)f2b(fa.w);
        xa[4] = (short)f2b(fb.x); xa[5] = (short)f2b(fb.y);
        xa[6] = (short)f2b(fb.z); xa[7] = (short)f2b(fb.w);
#pragma unroll
        for (int mh = 0; mh < 12; ++mh) {   // mh = mat*4 + hb
            const s16x8 wa = *(const s16x8*)(wt + (long)(mh * 16 + l15) * E_DIM + ke + g * 8);
            o[mh] = __builtin_amdgcn_mfma_f32_16x16x32_bf16(wa, xa, o[mh], 0, 0, 0);
        }
    }

    const long rg = row0 + l15;            // this lane's x-row (D column)
    const int batch = (int)(rg >> 12);
    const int sl = (int)(rg & 4095);
#pragma unroll
    for (int mat = 0; mat < 3; ++mat) {
        const float* bias = (mat == 0) ? bq : (mat == 1) ? bk : bv;
#pragma unroll
        for (int hb = 0; hb < 4; ++hb) {
            const f32x4 acc = o[mat * 4 + hb];
            const float4 bb = *(const float4*)(bias + hb * 16 + 4 * g);
            const float r0 = acc[0] + bb.x, r1 = acc[1] + bb.y;
            const float r2 = acc[2] + bb.z, r3 = acc[3] + bb.w;
            if (mat < 2) {
                u16* dst = ((mat == 0) ? qs : ks) + rg * H_DIM + hb * 16 + 4 * g;
                uint2 pk; pk.x = pk2(r0, r1); pk.y = pk2(r2, r3);
                *(uint2*)dst = pk;
            } else {
                const long hbase = (long)batch * H_DIM + hb * 16 + 4 * g;
                vt[(hbase + 0) * S_LEN + sl] = f2b(r0);
                vt[(hbase + 1) * S_LEN + sl] = f2b(r1);
                vt[(hbase + 2) * S_LEN + sl] = f2b(r2);
                vt[(hbase + 3) * S_LEN + sl] = f2b(r3);
            }
        }
    }
}

// ---------------------------------------------------------------------------
// Kernel 2: causal flash attention. One wave per 16 q-rows, zero LDS, zero
// barriers. All K/V operands are direct contiguous global loads (L2-resident;
// batch = blk&3 keeps each XCD on one batch). Register double-buffered tiles.
// QK^T transposed (mfma(K,Q)): D col = q = l15, row = key = 4g+r.
// PV via 16x16x16 (A-frag k=4g+j == QK D-layout: no P relayout needed).
// ---------------------------------------------------------------------------
#if USE_1K
typedef s16x4 vfrag;
#define NVB 8
#else
typedef s16x8 vfrag;
#define NVB 4
#endif

#define LOAD_K(KA, kv0_) do { \
    KA[0] = *(const s16x8*)(kb + (long)((kv0_) + l15) * H_DIM + g * 8); \
    KA[1] = *(const s16x8*)(kb + (long)((kv0_) + l15) * H_DIM + 32 + g * 8); \
    KA[2] = *(const s16x8*)(kb + (long)((kv0_) + 16 + l15) * H_DIM + g * 8); \
    KA[3] = *(const s16x8*)(kb + (long)((kv0_) + 16 + l15) * H_DIM + 32 + g * 8); \
} while (0)

#if USE_1K
#define LOAD_V(VB, kv0_) do { \
    _Pragma("unroll") \
    for (int c = 0; c < 4; ++c) { \
        VB[c]     = *(const s16x4*)(vtb + (long)(c * 16 + l15) * S_LEN + (kv0_) + 4 * g); \
        VB[4 + c] = *(const s16x4*)(vtb + (long)(c * 16 + l15) * S_LEN + (kv0_) + 16 + 4 * g); \
    } \
} while (0)
#else
#define LOAD_V(VB, kv0_) do { \
    _Pragma("unroll") \
    for (int c = 0; c < 4; ++c) \
        VB[c] = *(const s16x8*)(vtb + (long)(c * 16 + l15) * S_LEN + (kv0_) + 8 * g); \
} while (0)
#endif

#if USE_1K
#define PV(VB) do { \
    s16x4 pa0, pa1; \
    pa0[0] = (short)f2b(p[0]); pa0[1] = (short)f2b(p[1]); \
    pa0[2] = (short)f2b(p[2]); pa0[3] = (short)f2b(p[3]); \
    pa1[0] = (short)f2b(p[4]); pa1[1] = (short)f2b(p[5]); \
    pa1[2] = (short)f2b(p[6]); pa1[3] = (short)f2b(p[7]); \
    _Pragma("unroll") \
    for (int c = 0; c < 4; ++c) { \
        o[c] = __builtin_amdgcn_mfma_f32_16x16x16bf16_1k(pa0, VB[c], o[c], 0, 0, 0); \
        o[c] = __builtin_amdgcn_mfma_f32_16x16x16bf16_1k(pa1, VB[4 + c], o[c], 0, 0, 0); \
    } \
} while (0)
#else
// Build 16x16x32 A-frag (keys g*8..g*8+7 of q-row l15) via quad-exchange.
#define PV(VB) do { \
    const u32 w0 = pk2(p[0], p[1]), w1 = pk2(p[2], p[3]); \
    const u32 w2 = pk2(p[4], p[5]), w3 = pk2(p[6], p[7]); \
    const int srcA = ((g & 1) * 2) * 16 + l15, srcB = srcA + 16; \
    const u32 a0 = (u32)__shfl((int)w0, srcA, 64), a1 = (u32)__shfl((int)w1, srcA, 64); \
    const u32 a2 = (u32)__shfl((int)w2, srcA, 64), a3 = (u32)__shfl((int)w3, srcA, 64); \
    const u32 b0 = (u32)__shfl((int)w0, srcB, 64), b1 = (u32)__shfl((int)w1, srcB, 64); \
    const u32 b2 = (u32)__shfl((int)w2, srcB, 64), b3 = (u32)__shfl((int)w3, srcB, 64); \
    const bool losel = (g < 2); \
    const u32 d0 = losel ? a0 : a2, d1 = losel ? a1 : a3; \
    const u32 d2 = losel ? b0 : b2, d3 = losel ? b1 : b3; \
    s16x8 pa; \
    pa[0] = (short)(d0 & 0xffff); pa[1] = (short)(d0 >> 16); \
    pa[2] = (short)(d1 & 0xffff); pa[3] = (short)(d1 >> 16); \
    pa[4] = (short)(d2 & 0xffff); pa[5] = (short)(d2 >> 16); \
    pa[6] = (short)(d3 & 0xffff); pa[7] = (short)(d3 >> 16); \
    _Pragma("unroll") \
    for (int c = 0; c < 4; ++c) \
        o[c] = __builtin_amdgcn_mfma_f32_16x16x32_bf16(pa, VB[c], o[c], 0, 0, 0); \
} while (0)
#endif

#define TILE(KA, VB, kv0arg) do { \
    const int kv0 = (kv0arg); \
    f32x4 z = {0.f, 0.f, 0.f, 0.f}; \
    f32x4 st0 = __builtin_amdgcn_mfma_f32_16x16x32_bf16(KA[0], qa0, z, 0, 0, 0); \
    st0 = __builtin_amdgcn_mfma_f32_16x16x32_bf16(KA[1], qa1, st0, 0, 0, 0); \
    f32x4 st1 = __builtin_amdgcn_mfma_f32_16x16x32_bf16(KA[2], qa0, z, 0, 0, 0); \
    st1 = __builtin_amdgcn_mfma_f32_16x16x32_bf16(KA[3], qa1, st1, 0, 0, 0); \
    float p[8]; \
    if (kv0 + 31 > qw) { \
        _Pragma("unroll") \
        for (int r = 0; r < 4; ++r) { \
            p[r]     = (kv0 + 4 * g + r      <= qg) ? st0[r] * 0.125f : -INFINITY; \
            p[4 + r] = (kv0 + 16 + 4 * g + r <= qg) ? st1[r] * 0.125f : -INFINITY; \
        } \
    } else { \
        _Pragma("unroll") \
        for (int r = 0; r < 4; ++r) { p[r] = st0[r] * 0.125f; p[4 + r] = st1[r] * 0.125f; } \
    } \
    float pm = p[0]; \
    _Pragma("unroll") \
    for (int i = 1; i < 8; ++i) pm = fmaxf(pm, p[i]); \
    pm = fmaxf(pm, __shfl_xor(pm, 16, 64)); \
    pm = fmaxf(pm, __shfl_xor(pm, 32, 64)); \
    const float mnew = fmaxf(m, pm); \
    const float corr = __expf(m - mnew); \
    float psum = 0.f; \
    _Pragma("unroll") \
    for (int i = 0; i < 8; ++i) { p[i] = __expf(p[i] - mnew); psum += p[i]; } \
    psum += __shfl_xor(psum, 16, 64); \
    psum += __shfl_xor(psum, 32, 64); \
    lacc = lacc * corr + psum; \
    m = mnew; \
    _Pragma("unroll") \
    for (int r = 0; r < 4; ++r) { \
        const float cr = __shfl(corr, 4 * g + r, 64); \
        o[0][r] *= cr; o[1][r] *= cr; o[2][r] *= cr; o[3][r] *= cr; \
    } \
    PV(VB); \
} while (0)

__global__ __launch_bounds__(64) void attn_kernel(
    const u16* __restrict__ q, const u16* __restrict__ k,
    const u16* __restrict__ vt, float* __restrict__ out)
{
    const int lane = threadIdx.x;
    const int l15 = lane & 15, g = lane >> 4;
    const int blk = blockIdx.x;
    const int batch = blk & 3;                 // XCD (blk%8) -> fixed batch
    const int qt = 255 - (blk >> 2);           // longest tiles launch first
    const int qw = qt * 16;
    const int qg = qw + l15;
    const long base = (long)batch * S_LEN * H_DIM;
    const u16* kb = k + base;
    const u16* vtb = vt + (long)batch * H_DIM * S_LEN;

    const u16* qrow = q + base + (long)(qw + l15) * H_DIM;
    const s16x8 qa0 = *(const s16x8*)(qrow + g * 8);
    const s16x8 qa1 = *(const s16x8*)(qrow + 32 + g * 8);

    f32x4 o[4];
    f32x4 zz = {0.f, 0.f, 0.f, 0.f};
#pragma unroll
    for (int c = 0; c < 4; ++c) o[c] = zz;
    float m = -INFINITY, lacc = 0.f;
    const int T = qw / 32 + 1;

    s16x8 kaA[4], kaB[4];
    vfrag vbA[NVB], vbB[NVB];
    LOAD_K(kaA, 0);
    LOAD_V(vbA, 0);

    for (int t = 0; t < T; t += 2) {
        if (t + 1 < T) { LOAD_K(kaB, (t + 1) * 32); LOAD_V(vbB, (t + 1) * 32); }
        TILE(kaA, vbA, t * 32);
        if (t + 1 >= T) break;
        if (t + 2 < T) { LOAD_K(kaA, (t + 2) * 32); LOAD_V(vbA, (t + 2) * 32); }
        TILE(kaB, vbB, (t + 1) * 32);
    }

    float* ob = out + base;
#pragma unroll
    for (int r = 0; r < 4; ++r) {
        const float lr = __shfl(lacc, 4 * g + r, 64);
        const float inv = 1.0f / lr;
        const long row = qw + 4 * g + r;
#pragma unroll
        for (int c = 0; c < 4; ++c)
            ob[row * H_DIM + c * 16 + l15] = o[c][r] * inv;
    }
}

// ---------------------------------------------------------------------------
extern "C" void kernel_launch(void* const* d_in, const int* in_sizes, int n_in,
                              void* d_out, int out_size, void* d_ws, size_t ws_size,
                              hipStream_t stream)
{
    const float* x  = (const float*)d_in[0];
    const float* Wq = (const float*)d_in[1];
    const float* bq = (const float*)d_in[2];
    const float* Wk = (const float*)d_in[3];
    const float* bk = (const float*)d_in[4];
    const float* Wv = (const float*)d_in[5];
    const float* bv = (const float*)d_in[6];
    float* out = (float*)d_out;

    const long BSH = (long)B_SZ * S_LEN * H_DIM;   // 1,048,576
    u16* qs = (u16*)d_ws;
    u16* ks = qs + BSH;
    u16* vt = ks + BSH;
    u16* wt = vt + BSH;

    wt_kernel<<<768, 256, 0, stream>>>(Wq, Wk, Wv, wt);
    proj_kernel<<<B_SZ * S_LEN / 16, 64, 0, stream>>>(x, wt, bq, bk, bv, qs, ks, vt);
    attn_kernel<<<B_SZ * S_LEN / 16, 64, 0, stream>>>(qs, ks, vt, out);
}